// Round 10
// baseline (419.885 us; speedup 1.0000x reference)
//
#include <hip/hip_runtime.h>
#include <hip/hip_fp16.h>
#include <cstdint>
#include <cstddef>

// Problem constants (fixed by the reference generator)
#define DD 64           // feature dim D == A
#define N_RELTAB 401    // rel_emb rows
#define N_QR 8          // batchsize B
#define T_ROWS (N_RELTAB + N_QR)   // 409 f32 rows: C[0..400], Q[401..408]
#define CHUNK 32        // edges per wave in fused_aggregate
#define WPB 4           // waves per block in fused_aggregate

__device__ __forceinline__ uint16_t f2bf(float f) {
    uint32_t u = __float_as_uint(f);
    u += 0x7fffu + ((u >> 16) & 1u);     // RNE
    return (uint16_t)(u >> 16);
}
__device__ __forceinline__ float bf2f(uint16_t u) {
    return __uint_as_float(((uint32_t)u) << 16);
}

// K0: Cf[r]  = Wr . rel_emb[r]                      (r < 401)
//     Cf[401+k] = Wqr . rel_emb[q_rel[k]] + Wqr_b   (k < 8)
//     RWh[r] = Wh . rel_emb[r]                      (r < 401)   (all f32)
__global__ __launch_bounds__(64) void build_tables(
    const float* __restrict__ rel_emb, const float* __restrict__ Wr,
    const float* __restrict__ Wqr_w, const float* __restrict__ Wqr_b,
    const int* __restrict__ q_rel, const float* __restrict__ Wh,
    float* __restrict__ Cf, float* __restrict__ RWh)
{
    int r = blockIdx.x, a = threadIdx.x;
    if (r < N_RELTAB) {
        const float* src = rel_emb + r * DD;
        const float* w1 = Wr + a * DD;
        const float* w2 = Wh + a * DD;
        float a1 = 0.f, a2 = 0.f;
#pragma unroll
        for (int d = 0; d < DD; ++d) {
            float s = src[d];
            a1 = fmaf(s, w1[d], a1);
            a2 = fmaf(s, w2[d], a2);
        }
        Cf[r * DD + a] = a1;
        RWh[r * DD + a] = a2;
    } else {
        int k = r - N_RELTAB;
        const float* src = rel_emb + q_rel[k] * DD;  // block-uniform
        const float* w = Wqr_w + a * DD;
        float acc = Wqr_b[a];
#pragma unroll
        for (int d = 0; d < DD; ++d) acc = fmaf(src[d], w[d], acc);
        Cf[r * DD + a] = acc;
    }
}

// K1: hidden -> Xb (bf16, Ws.h) and HWh (f32, Wh.h).
// SINGLE-SHOT version (round-10): one 64-node tile per block; stage once,
// one barrier, compute, exit. Round-9's grid-stride loop reused the LDS
// staging buffer across iterations and produced a NON-DETERMINISTIC absmax
// failure (race on the reused buffer); removing the loop removes the race
// surface. Weights stay in per-lane VGPRs (lane = output feature; 128 regs,
// static-indexed) so the inner loop has ZERO weight VMEM by construction.
__global__ __launch_bounds__(256) void prep(
    const float* __restrict__ in, const float* __restrict__ Ws,
    const float* __restrict__ Wh, uint16_t* __restrict__ Xb,
    float* __restrict__ HWh, int nrows)
{
    __shared__ float4 sIn4[DD][17];     // 64 rows x 16 float4 (+1 pad), 17.4 KB
    int t = threadIdx.x;
    int lane = t & 63, wid = t >> 6;
    int r0 = blockIdx.x * DD;
    int vr = nrows - r0; if (vr > DD) vr = DD;

    // Preload weight rows into registers (once per thread).
    float wS[DD], wH[DD];
    {
        const float4* p1 = (const float4*)(Ws + lane * DD);
        const float4* p2 = (const float4*)(Wh + lane * DD);
#pragma unroll
        for (int i = 0; i < DD / 4; ++i) {
            float4 v = p1[i];
            wS[4*i+0] = v.x; wS[4*i+1] = v.y; wS[4*i+2] = v.z; wS[4*i+3] = v.w;
            float4 u = p2[i];
            wH[4*i+0] = u.x; wH[4*i+1] = u.y; wH[4*i+2] = u.z; wH[4*i+3] = u.w;
        }
    }

    // stage 64 rows, coalesced
    const float4* gin = (const float4*)(in + (size_t)r0 * DD);
    int vf4 = vr * (DD / 4);
#pragma unroll
    for (int k = 0; k < 4; ++k) {
        int f = t + k * 256;
        if (f < vf4) sIn4[f >> 4][f & 15] = gin[f];
    }
    __syncthreads();

    // wave wid computes nodes [wid*16, wid*16+16); lane = feature
#pragma unroll 1
    for (int i = 0; i < 16; ++i) {
        int nl = wid * 16 + i;
        if (nl >= vr) break;
        float accX = 0.f, accH = 0.f;
#pragma unroll
        for (int j = 0; j < 16; ++j) {
            float4 v = sIn4[nl][j];  // wave-uniform addr -> LDS broadcast
            accX = fmaf(v.x, wS[4*j+0], accX);
            accX = fmaf(v.y, wS[4*j+1], accX);
            accX = fmaf(v.z, wS[4*j+2], accX);
            accX = fmaf(v.w, wS[4*j+3], accX);
            accH = fmaf(v.x, wH[4*j+0], accH);
            accH = fmaf(v.y, wH[4*j+1], accH);
            accH = fmaf(v.z, wH[4*j+2], accH);
            accH = fmaf(v.w, wH[4*j+3], accH);
        }
        size_t n = (size_t)(r0 + nl);
        Xb[(n << 6) + lane] = f2bf(accX);
        HWh[(n << 6) + lane] = accH;
    }
}

// K2: histogram of obj + emit compact keys (pay | obj<<32).
// Fully-coalesced int4 reads, 2 edges per thread (edge row = 6 ints).
__global__ __launch_bounds__(256) void hist_emit(
    const int4* __restrict__ edges4, int* __restrict__ counts,
    uint64_t* __restrict__ keys, int n_edge)
{
    int t = blockIdx.x * 256 + threadIdx.x;
    int e0 = 2 * t;
    if (e0 >= n_edge) return;
    int4 a = edges4[3 * t];          // e0: r_idx, head, rel, tail
    int4 b = edges4[3 * t + 1];      // e0: sub, obj ; e1: r_idx, head
    // edge e0
    {
        uint32_t pay = (uint32_t)b.x | ((uint32_t)a.z << 17) | ((uint32_t)a.x << 26);
        atomicAdd(&counts[b.y], 1);
        keys[e0] = (uint64_t)pay | ((uint64_t)(uint32_t)b.y << 32);
    }
    // edge e0+1
    if (e0 + 1 < n_edge) {
        int4 c = edges4[3 * t + 2];  // e1: rel, tail, sub, obj
        uint32_t pay = (uint32_t)c.z | ((uint32_t)c.x << 17) | ((uint32_t)b.z << 26);
        atomicAdd(&counts[c.w], 1);
        keys[e0 + 1] = (uint64_t)pay | ((uint64_t)(uint32_t)c.w << 32);
    }
}

// K3: per-chunk exclusive scan (chunk = 1024), block-local excl + block sums
__global__ __launch_bounds__(1024) void scan1(
    const int* __restrict__ counts, int* __restrict__ offsets,
    int* __restrict__ bsums, int n)
{
    __shared__ int wsum[16];
    int t = threadIdx.x, i = blockIdx.x * 1024 + t;
    int lane = t & 63, wid = t >> 6;
    int c = (i < n) ? counts[i] : 0;
    int v = c;
#pragma unroll
    for (int d = 1; d < 64; d <<= 1) { int u = __shfl_up(v, d); if (lane >= d) v += u; }
    if (lane == 63) wsum[wid] = v;
    __syncthreads();
    if (wid == 0) {
        int s = (lane < 16) ? wsum[lane] : 0;
#pragma unroll
        for (int d = 1; d < 16; d <<= 1) { int u = __shfl_up(s, d); if (lane >= d) s += u; }
        if (lane < 16) wsum[lane] = s;
    }
    __syncthreads();
    int woff = (wid == 0) ? 0 : wsum[wid - 1];
    if (i < n) offsets[i] = woff + v - c;
    if (t == 1023) bsums[blockIdx.x] = wsum[15];
}

// K4: parallel single-block exclusive scan of block sums (nb <= 1024)
__global__ __launch_bounds__(1024) void scan_small(
    const int* __restrict__ bsums, int* __restrict__ boffs, int nb)
{
    __shared__ int wsum[16];
    int t = threadIdx.x, lane = t & 63, wid = t >> 6;
    int c = (t < nb) ? bsums[t] : 0;
    int v = c;
#pragma unroll
    for (int d = 1; d < 64; d <<= 1) { int u = __shfl_up(v, d); if (lane >= d) v += u; }
    if (lane == 63) wsum[wid] = v;
    __syncthreads();
    if (wid == 0) {
        int s = (lane < 16) ? wsum[lane] : 0;
#pragma unroll
        for (int d = 1; d < 16; d <<= 1) { int u = __shfl_up(s, d); if (lane >= d) s += u; }
        if (lane < 16) wsum[lane] = s;
    }
    __syncthreads();
    int woff = (wid == 0) ? 0 : wsum[wid - 1];
    if (t < nb) boffs[t] = woff + v - c;
}

// K5: add block offsets; init cursor; fill node_of_pos runs (merged fill_runs)
__global__ __launch_bounds__(1024) void scan3_fill(
    int* __restrict__ offsets, int* __restrict__ cursor,
    const int* __restrict__ boffs, const int* __restrict__ counts,
    uint32_t* __restrict__ node_of_pos, int n)
{
    int i = blockIdx.x * 1024 + threadIdx.x;
    if (i < n) {
        int v = offsets[i] + boffs[blockIdx.x];
        offsets[i] = v;
        cursor[i] = v;
        int c = counts[i];
        for (int k = 0; k < c; ++k) node_of_pos[v + k] = (uint32_t)i;
    }
}

// K6: counting-sort: scatter u32 payload only (obj recoverable from position)
__global__ __launch_bounds__(256) void build_sorted(
    const uint64_t* __restrict__ keys, int* __restrict__ cursor,
    uint32_t* __restrict__ sorted_pay, int n_edge)
{
    int e = blockIdx.x * 256 + threadIdx.x;
    if (e >= n_edge) return;
    uint64_t k = keys[e];
    int obj = (int)(k >> 32);
    int pos = atomicAdd(&cursor[obj], 1);
    sorted_pay[pos] = (uint32_t)k;
}

// K7: fused alpha + segmented aggregation DIRECTLY into out (Wh folded in via
// HWh/RWh tables). One wave per 32 obj-sorted edges; per-edge scalars via
// v_readlane. Phase A (lane=feature): relu(x+c+q)*wa -> LDS f16.
// Phase B (lane=edge&31, half=lane>>5): row-sum + 1 shfl -> alpha.
// Phase C (lane=feature): out += alpha*(HWh[sub]+RWh[rel]), plain store
// interior segments / atomic at chunk boundaries.
__global__ __launch_bounds__(256, 4) void fused_aggregate(
    const uint32_t* __restrict__ sorted_pay, const uint32_t* __restrict__ node_of_pos,
    const uint16_t* __restrict__ Xb, const float* __restrict__ HWh,
    const float* __restrict__ Cf, const float* __restrict__ RWh,
    const float* __restrict__ walpha_w, const float* __restrict__ walpha_b,
    float* __restrict__ out, int n_edge, int n_node)
{
    __shared__ float sQ[N_QR * DD];               // 2 KB
    __shared__ __half sS[WPB][CHUNK][DD + 2];     // 16.9 KB
    int tid = threadIdx.x, lane = tid & 63, wid = tid >> 6;
    for (int i = tid; i < N_QR * DD; i += 64 * WPB) sQ[i] = Cf[N_RELTAB * DD + i];
    __syncthreads();

    long chunk = (long)blockIdx.x * WPB + wid;
    long base = chunk * CHUNK;
    if (base >= n_edge) return;

    int e_l = (int)base + (lane & 31);
    uint32_t pay = 0;
    int obj = n_node;                              // sentinel
    if (lane < 32 && e_l < n_edge) {
        pay = sorted_pay[e_l];
        obj = (int)node_of_pos[e_l];
    }

    float wa = walpha_w[lane];
    float wb = walpha_b[0];

    // ---- Phase A ----
#pragma unroll 8
    for (int j = 0; j < CHUNK; ++j) {
        uint32_t pj = (uint32_t)__builtin_amdgcn_readlane((int)pay, j);
        int sub  = (int)(pj & 0x1FFFFu);
        int rel  = (int)((pj >> 17) & 0x1FFu);
        int ridx = (int)((pj >> 26) & 7u);
        float x = bf2f(Xb[((size_t)sub << 6) + lane]);
        float c = Cf[(rel << 6) + lane];
        float q = sQ[(ridx << 6) + lane];
        sS[wid][j][lane] = __float2half(fmaxf(x + c + q, 0.f) * wa);
    }

    // ---- Phase B ----
    int eb = lane & 31, hb = lane >> 5;
    const __half2* row2 = (const __half2*)&sS[wid][eb][hb * 32];
    float tsum = 0.f;
#pragma unroll
    for (int a2 = 0; a2 < 16; ++a2) {
        float2 f = __half22float2(row2[a2]);
        tsum += f.x + f.y;
    }
    tsum += __shfl_xor(tsum, 32);
    float alpha = 1.f / (1.f + __expf(-(tsum + wb)));   // lanes j, j+32 hold edge j

    // ---- Phase C ----
    float acc = 0.f;
    int prev = __builtin_amdgcn_readlane(obj, 0);
    bool first = true;
#pragma unroll 8
    for (int j = 0; j < CHUNK; ++j) {
        int oj = __builtin_amdgcn_readlane(obj, j);
        if (oj != prev) {
            if (prev < n_node) {
                float* dst = &out[((size_t)prev << 6) + lane];
                if (first) atomicAdd(dst, acc); else *dst = acc;
            }
            first = false; acc = 0.f; prev = oj;
        }
        if (oj < n_node) {
            uint32_t pj = (uint32_t)__builtin_amdgcn_readlane((int)pay, j);
            int sub = (int)(pj & 0x1FFFFu);
            int rel = (int)((pj >> 17) & 0x1FFu);
            float h = HWh[((size_t)sub << 6) + lane];
            float r = RWh[(rel << 6) + lane];
            float aj = __uint_as_float(
                (uint32_t)__builtin_amdgcn_readlane((int)__float_as_uint(alpha), j));
            acc = fmaf(aj, h + r, acc);
        }
    }
    if (prev < n_node) atomicAdd(&out[((size_t)prev << 6) + lane], acc);
}

extern "C" void kernel_launch(void* const* d_in, const int* in_sizes, int n_in,
                              void* d_out, int out_size, void* d_ws, size_t ws_size,
                              hipStream_t stream)
{
    const int*   q_rel    = (const int*)d_in[1];
    const float* hidden   = (const float*)d_in[2];
    const int*   edges    = (const int*)d_in[3];
    const float* rel_emb  = (const float*)d_in[7];
    const float* Ws       = (const float*)d_in[8];
    const float* Wr       = (const float*)d_in[9];
    const float* Wqr_w    = (const float*)d_in[10];
    const float* Wqr_b    = (const float*)d_in[11];
    const float* walpha_w = (const float*)d_in[12];
    const float* walpha_b = (const float*)d_in[13];
    const float* Wh       = (const float*)d_in[14];
    float* out = (float*)d_out;

    const int n_node = in_sizes[2] / DD;   // 100000
    const int n_edge = in_sizes[3] / 6;    // 1000000
    const int NB = (n_node + 1023) / 1024; // scan chunks (98)

    // ws layout (all segments 64 B multiples), ~55 MB total:
    char* w = (char*)d_ws;
    uint16_t* Xb      = (uint16_t*)w;  w += (size_t)n_node * DD * 2;   // 12.8 MB
    float*    HWh     = (float*)w;     w += (size_t)n_node * DD * 4;   // 25.6 MB
    uint64_t* keys    = (uint64_t*)w;  w += (size_t)n_edge * 8;        // 8 MB
    uint32_t* spay    = (uint32_t*)w;  w += (size_t)n_edge * 4;        // 4 MB
    uint32_t* npos    = (uint32_t*)w;  w += (size_t)n_edge * 4;        // 4 MB
    int*      counts  = (int*)w;       w += (size_t)n_node * 4;
    int*      offsets = (int*)w;       w += (size_t)n_node * 4;
    int*      cursor  = (int*)w;       w += (size_t)n_node * 4;
    int*      bsums   = (int*)w;       w += 4096;
    int*      boffs   = (int*)w;       w += 4096;
    float*    Cf      = (float*)w;     w += (size_t)T_ROWS * DD * 4;   // 104.7 KB
    float*    RWh     = (float*)w;     w += (size_t)N_RELTAB * DD * 4; // 102.7 KB

    build_tables<<<T_ROWS, 64, 0, stream>>>(rel_emb, Wr, Wqr_w, Wqr_b, q_rel, Wh,
                                            Cf, RWh);
    prep<<<(n_node + DD - 1) / DD, 256, 0, stream>>>(hidden, Ws, Wh, Xb, HWh, n_node);
    hipMemsetAsync(counts, 0, (size_t)n_node * 4, stream);
    hipMemsetAsync(out, 0, (size_t)out_size * 4, stream);
    const int npair = (n_edge + 1) / 2;
    hist_emit<<<(npair + 255) / 256, 256, 0, stream>>>(
        (const int4*)edges, counts, keys, n_edge);
    scan1<<<NB, 1024, 0, stream>>>(counts, offsets, bsums, n_node);
    scan_small<<<1, 1024, 0, stream>>>(bsums, boffs, NB);
    scan3_fill<<<NB, 1024, 0, stream>>>(offsets, cursor, boffs, counts, npos, n_node);
    build_sorted<<<(n_edge + 255) / 256, 256, 0, stream>>>(keys, cursor, spay, n_edge);
    const int nchunks = (n_edge + CHUNK - 1) / CHUNK;       // 31250
    fused_aggregate<<<(nchunks + WPB - 1) / WPB, 64 * WPB, 0, stream>>>(
        spay, npos, Xb, HWh, Cf, RWh, walpha_w, walpha_b, out, n_edge, n_node);
}